// Round 1
// baseline (767.491 us; speedup 1.0000x reference)
//
#include <hip/hip_runtime.h>

// Problem constants
#define BATCH 4
#define NSEQ 2048
#define MSEQ 2048
#define DIM 1024
#define HEADS 16
#define DHEAD 64
#define INNER 1024
#define KVLEN 2049          // null token + MSEQ
#define KVPAD 2176          // 17 * 128

typedef unsigned short u16;
typedef unsigned int u32;
typedef __bf16 bf16x8 __attribute__((ext_vector_type(8)));
typedef float f32x4 __attribute__((ext_vector_type(4)));

__device__ inline u16 f2bf(float f) {
  u32 u = __builtin_bit_cast(u32, f);
  u = (u + 0x7fffu + ((u >> 16) & 1u)) >> 16;
  return (u16)u;
}

// ---------------- LayerNorm (row of 1024), output bf16 or fp32 ----------------
template <bool OUT_BF16>
__global__ __launch_bounds__(256) void ln_kernel(const float* __restrict__ x,
                                                 const float* __restrict__ g,
                                                 void* __restrict__ out) {
  const int row = blockIdx.x;
  const int t = threadIdx.x;
  const float4 v = ((const float4*)(x + (size_t)row * 1024))[t];
  float sum = v.x + v.y + v.z + v.w;
  float sq = v.x * v.x + v.y * v.y + v.z * v.z + v.w * v.w;
  for (int m = 1; m < 64; m <<= 1) {
    sum += __shfl_xor(sum, m, 64);
    sq += __shfl_xor(sq, m, 64);
  }
  __shared__ float red[8];
  const int w = t >> 6, l = t & 63;
  if (l == 0) { red[w] = sum; red[4 + w] = sq; }
  __syncthreads();
  sum = red[0] + red[1] + red[2] + red[3];
  sq = red[4] + red[5] + red[6] + red[7];
  const float mean = sum * (1.0f / 1024.0f);
  const float var = sq * (1.0f / 1024.0f) - mean * mean;
  const float rstd = rsqrtf(var + 1e-5f);
  const float4 gv = ((const float4*)g)[t];
  float o0 = (v.x - mean) * rstd * gv.x;
  float o1 = (v.y - mean) * rstd * gv.y;
  float o2 = (v.z - mean) * rstd * gv.z;
  float o3 = (v.w - mean) * rstd * gv.w;
  if (OUT_BF16) {
    ushort4 ov;
    ov.x = f2bf(o0); ov.y = f2bf(o1); ov.z = f2bf(o2); ov.w = f2bf(o3);
    ((ushort4*)((u16*)out + (size_t)row * 1024))[t] = ov;
  } else {
    float4 ov;
    ov.x = o0; ov.y = o1; ov.z = o2; ov.w = o3;
    ((float4*)((float*)out + (size_t)row * 1024))[t] = ov;
  }
}

// ---------------- fp32 -> bf16 cast (vectorized by 4) ----------------
__global__ __launch_bounds__(256) void cast_bf16(const float* __restrict__ in,
                                                 u16* __restrict__ out, int n4) {
  int i = blockIdx.x * 256 + threadIdx.x;
  if (i < n4) {
    float4 v = ((const float4*)in)[i];
    ushort4 o;
    o.x = f2bf(v.x); o.y = f2bf(v.y); o.z = f2bf(v.z); o.w = f2bf(v.w);
    ((ushort4*)out)[i] = o;
  }
}

// ---------------- W[K][N] fp32 -> WT[N][K] bf16 (tiled transpose) ----------------
__global__ __launch_bounds__(256) void transpose_cast(const float* __restrict__ W,
                                                      u16* __restrict__ WT, int K, int N) {
  __shared__ float tile[32][33];
  const int tx = threadIdx.x & 31, ty = threadIdx.x >> 5;  // ty 0..7
  const int k0 = blockIdx.y * 32, n0 = blockIdx.x * 32;
  for (int r = ty; r < 32; r += 8) tile[r][tx] = W[(size_t)(k0 + r) * N + n0 + tx];
  __syncthreads();
  for (int r = ty; r < 32; r += 8) WT[(size_t)(n0 + r) * K + k0 + tx] = f2bf(tile[tx][r]);
}

// ---------------- bf16 GEMM: C[M][N] = A[M][K] @ Bt[N][K]^T, fp32 out ----------------
// 128x128 tile, BK=32, 4 waves in 2x2, each wave 4x4 of 16x16x32 MFMA.
__global__ __launch_bounds__(256) void gemm_bt(const u16* __restrict__ A,
                                               const u16* __restrict__ Bt,
                                               float* __restrict__ C,
                                               int M, int N, int K) {
  __shared__ __align__(16) u16 As[128 * 32];
  __shared__ __align__(16) u16 Bs[128 * 32];
  const int t = threadIdx.x;
  const int w = t >> 6, l = t & 63, l15 = l & 15, lq = l >> 4;
  const int m0 = blockIdx.y * 128, n0 = blockIdx.x * 128;
  const int wm = (w >> 1) * 64, wn = (w & 1) * 64;
  f32x4 acc[4][4] = {};
  for (int k0 = 0; k0 < K; k0 += 32) {
#pragma unroll
    for (int c = t; c < 512; c += 256) {
      int row = c >> 2, ko = (c & 3) * 8;
      *(uint4*)&As[row * 32 + ko] = *(const uint4*)&A[(size_t)(m0 + row) * K + k0 + ko];
      *(uint4*)&Bs[row * 32 + ko] = *(const uint4*)&Bt[(size_t)(n0 + row) * K + k0 + ko];
    }
    __syncthreads();
    bf16x8 af[4], bfr[4];
#pragma unroll
    for (int i = 0; i < 4; i++) af[i] = *(bf16x8*)&As[(wm + i * 16 + l15) * 32 + lq * 8];
#pragma unroll
    for (int j = 0; j < 4; j++) bfr[j] = *(bf16x8*)&Bs[(wn + j * 16 + l15) * 32 + lq * 8];
#pragma unroll
    for (int i = 0; i < 4; i++)
#pragma unroll
      for (int j = 0; j < 4; j++)
        acc[i][j] = __builtin_amdgcn_mfma_f32_16x16x32_bf16(af[i], bfr[j], acc[i][j], 0, 0, 0);
    __syncthreads();
  }
#pragma unroll
  for (int i = 0; i < 4; i++)
#pragma unroll
    for (int j = 0; j < 4; j++)
#pragma unroll
      for (int r = 0; r < 4; r++)
        C[(size_t)(m0 + wm + i * 16 + lq * 4 + r) * N + n0 + wn + j * 16 + l15] = acc[i][j][r];
}

// ---------------- q post: l2norm * q_scale * SCALE -> qn[b,h,n,64] bf16 ----------------
__global__ __launch_bounds__(64) void q_post(const float* __restrict__ qg,
                                             const float* __restrict__ q_scale,
                                             u16* __restrict__ qn) {
  const int idx = blockIdx.x;
  const int h = idx & 15, row = idx >> 4;  // row = b*2048 + n
  const int d = threadIdx.x;
  float v = qg[(size_t)row * 1024 + h * 64 + d];
  float ss = v * v;
  for (int m = 1; m < 64; m <<= 1) ss += __shfl_xor(ss, m, 64);
  float inv = 1.0f / fmaxf(sqrtf(ss), 1e-12f);
  float o = v * inv * q_scale[d] * 8.0f;
  const int b = row >> 11, n = row & 2047;
  qn[(((size_t)b * 16 + h) * 2048 + n) * 64 + d] = f2bf(o);
}

// ---------------- k post: l2norm * k_scale -> kn[b,h,m+1,64] bf16 ----------------
__global__ __launch_bounds__(64) void k_post(const float* __restrict__ kvg,
                                             const float* __restrict__ k_scale,
                                             u16* __restrict__ kn) {
  const int idx = blockIdx.x;
  const int h = idx & 15, row = idx >> 4;  // row = b*2048 + m
  const int d = threadIdx.x;
  float v = kvg[(size_t)row * 2048 + h * 64 + d];
  float ss = v * v;
  for (int m = 1; m < 64; m <<= 1) ss += __shfl_xor(ss, m, 64);
  float inv = 1.0f / fmaxf(sqrtf(ss), 1e-12f);
  float o = v * inv * k_scale[d];
  const int b = row >> 11, mm = row & 2047;
  kn[(((size_t)b * 16 + h) * (size_t)KVPAD + (mm + 1)) * 64 + d] = f2bf(o);
}

// ---------------- v post: transpose to vt[b,h,64,KVPAD] bf16 (offset +1 for null) ----------------
__global__ __launch_bounds__(256) void v_post(const float* __restrict__ kvg,
                                              u16* __restrict__ vt) {
  __shared__ float tile[64][65];
  const int bh = blockIdx.y, mt = blockIdx.x;
  const int tx = threadIdx.x & 63, ty = threadIdx.x >> 6;
  const int b = bh >> 4, h = bh & 15;
  const int m0 = mt * 64;
  for (int r = ty; r < 64; r += 4)
    tile[tx][r] = kvg[(size_t)(b * 2048 + m0 + r) * 2048 + 1024 + h * 64 + tx];
  __syncthreads();
  for (int d = ty; d < 64; d += 4)
    vt[((size_t)bh * 64 + d) * KVPAD + 1 + m0 + tx] = f2bf(tile[d][tx]);
}

// ---------------- null token + tail zeroing ----------------
__global__ __launch_bounds__(64) void null_tail(const float* __restrict__ null_kv,
                                                const float* __restrict__ k_scale,
                                                u16* __restrict__ kn, u16* __restrict__ vt) {
  const int bh = blockIdx.x, d = threadIdx.x;
  float nk = null_kv[d];
  float nv = null_kv[64 + d];
  float ss = nk * nk;
  for (int m = 1; m < 64; m <<= 1) ss += __shfl_xor(ss, m, 64);
  float inv = 1.0f / fmaxf(sqrtf(ss), 1e-12f);
  kn[((size_t)bh * KVPAD) * 64 + d] = f2bf(nk * inv * k_scale[d]);
  vt[((size_t)bh * 64 + d) * KVPAD] = f2bf(nv);
  for (int m = KVLEN; m < KVPAD; m++) kn[((size_t)bh * KVPAD + m) * 64 + d] = 0;
  u16* vrow = vt + ((size_t)bh * 64 + d) * KVPAD;
  for (int m = KVLEN; m < KVPAD; m++) vrow[m] = 0;
}

// ---------------- flash attention: Q tile 64 rows, KV tiles of 128, 17 iters ----------------
__global__ __launch_bounds__(256) void attn_kernel(const u16* __restrict__ qn,
                                                   const u16* __restrict__ kn,
                                                   const u16* __restrict__ vt,
                                                   u16* __restrict__ aout) {
  __shared__ __align__(16) u16 Qs[64 * 64];
  __shared__ __align__(16) u16 Ks[128 * 64];
  __shared__ __align__(16) u16 Vs[64 * 128];
  __shared__ __align__(16) u16 Ps[64 * 128];
  const int qt = blockIdx.x, bh = blockIdx.y;
  const int b = bh >> 4, h = bh & 15;
  const int t = threadIdx.x, w = t >> 6, l = t & 63, l15 = l & 15, lq = l >> 4;

  const u16* qbase = qn + ((size_t)bh * 2048 + qt * 64) * 64;
#pragma unroll
  for (int c = t; c < 512; c += 256)
    *(uint4*)&Qs[c * 8] = *(const uint4*)&qbase[c * 8];

  f32x4 O[4] = {};
  f32x4 mrow = {-1e30f, -1e30f, -1e30f, -1e30f};
  f32x4 lrow = {0.f, 0.f, 0.f, 0.f};

  for (int kt = 0; kt < 17; kt++) {
    const u16* kbase = kn + ((size_t)bh * KVPAD + kt * 128) * 64;
#pragma unroll
    for (int c = t; c < 1024; c += 256)
      *(uint4*)&Ks[c * 8] = *(const uint4*)&kbase[c * 8];
#pragma unroll
    for (int c = t; c < 1024; c += 256) {
      int d = c >> 4, off = (c & 15) * 8;
      *(uint4*)&Vs[d * 128 + off] =
          *(const uint4*)&vt[((size_t)bh * 64 + d) * KVPAD + kt * 128 + off];
    }
    __syncthreads();

    // S = Q K^T  (wave w owns q rows w*16..w*16+15)
    f32x4 S[8] = {};
#pragma unroll
    for (int ks = 0; ks < 2; ks++) {
      bf16x8 aq = *(bf16x8*)&Qs[(w * 16 + l15) * 64 + ks * 32 + lq * 8];
#pragma unroll
      for (int j = 0; j < 8; j++) {
        bf16x8 bk = *(bf16x8*)&Ks[(j * 16 + l15) * 64 + ks * 32 + lq * 8];
        S[j] = __builtin_amdgcn_mfma_f32_16x16x32_bf16(aq, bk, S[j], 0, 0, 0);
      }
    }
    if (kt == 16) {
      // only global col 2048 (j==0 && l15==0) is valid in the last tile
#pragma unroll
      for (int j = 0; j < 8; j++)
        if (j > 0 || l15 > 0) {
#pragma unroll
          for (int r = 0; r < 4; r++) S[j][r] = -1e30f;
        }
    }
    // online softmax per row slot (row = w*16 + lq*4 + r)
    float al[4];
#pragma unroll
    for (int r = 0; r < 4; r++) {
      float smax = S[0][r];
#pragma unroll
      for (int j = 1; j < 8; j++) smax = fmaxf(smax, S[j][r]);
#pragma unroll
      for (int m = 1; m < 16; m <<= 1) smax = fmaxf(smax, __shfl_xor(smax, m, 64));
      float mnew = fmaxf(mrow[r], smax);
      float alpha = __expf(mrow[r] - mnew);
      mrow[r] = mnew;
      float rsum = 0.f;
#pragma unroll
      for (int j = 0; j < 8; j++) {
        float p = __expf(S[j][r] - mnew);
        S[j][r] = p;
        rsum += p;
      }
#pragma unroll
      for (int m = 1; m < 16; m <<= 1) rsum += __shfl_xor(rsum, m, 64);
      lrow[r] = lrow[r] * alpha + rsum;
      al[r] = alpha;
    }
#pragma unroll
    for (int nt = 0; nt < 4; nt++)
#pragma unroll
      for (int r = 0; r < 4; r++) O[nt][r] *= al[r];
    // P -> LDS (C-layout -> A-layout round trip)
#pragma unroll
    for (int j = 0; j < 8; j++)
#pragma unroll
      for (int r = 0; r < 4; r++)
        Ps[(w * 16 + lq * 4 + r) * 128 + j * 16 + l15] = f2bf(S[j][r]);
    __syncthreads();
    // O += P V
#pragma unroll
    for (int ks = 0; ks < 4; ks++) {
      bf16x8 ap = *(bf16x8*)&Ps[(w * 16 + l15) * 128 + ks * 32 + lq * 8];
#pragma unroll
      for (int nt = 0; nt < 4; nt++) {
        bf16x8 bv = *(bf16x8*)&Vs[(nt * 16 + l15) * 128 + ks * 32 + lq * 8];
        O[nt] = __builtin_amdgcn_mfma_f32_16x16x32_bf16(ap, bv, O[nt], 0, 0, 0);
      }
    }
    __syncthreads();  // protect Ks/Vs/Ps before next stage
  }
  // epilogue: write [b, n, h*64+d] bf16
#pragma unroll
  for (int nt = 0; nt < 4; nt++)
#pragma unroll
    for (int r = 0; r < 4; r++) {
      int row = qt * 64 + w * 16 + lq * 4 + r;
      int col = h * 64 + nt * 16 + l15;
      float val = O[nt][r] / lrow[r];
      aout[((size_t)b * 2048 + row) * 1024 + col] = f2bf(val);
    }
}

// ---------------- host launch ----------------
extern "C" void kernel_launch(void* const* d_in, const int* in_sizes, int n_in,
                              void* d_out, int out_size, void* d_ws, size_t ws_size,
                              hipStream_t stream) {
  const float* x = (const float*)d_in[0];
  const float* context = (const float*)d_in[1];
  const float* g_norm = (const float*)d_in[2];
  const float* null_kv = (const float*)d_in[3];
  // Wq=d_in[4], Wkv=d_in[5], q_scale=d_in[6], k_scale=d_in[7], Wout=d_in[8], g_out=d_in[9]
  const float* Wq = (const float*)d_in[4];
  const float* Wkv = (const float*)d_in[5];
  const float* q_scale = (const float*)d_in[6];
  const float* k_scale = (const float*)d_in[7];
  const float* Wout = (const float*)d_in[8];
  const float* g_out = (const float*)d_in[9];
  float* out = (float*)d_out;

  char* ws = (char*)d_ws;
  u16* xn = (u16*)(ws);                      // 16,777,216 B
  u16* ctxb = (u16*)(ws + 16777216);         // 16,777,216
  u16* wqT = (u16*)(ws + 33554432);          // 2,097,152
  u16* wkvT = (u16*)(ws + 35651584);         // 4,194,304
  u16* woutT = (u16*)(ws + 39845888);        // 2,097,152
  float* qg = (float*)(ws + 41943040);       // 33,554,432
  float* kvg = (float*)(ws + 75497472);      // 67,108,864
  u16* qnb = (u16*)(ws + 142606336);         // 16,777,216
  u16* knb = (u16*)(ws + 159383552);         // 17,825,792
  u16* vtb = (u16*)(ws + 177209344);         // 17,825,792  -> total 195,035,136
  u16* attn_out = (u16*)qg;                  // reuse (qg consumed by q_post)
  float* outg = kvg;                         // reuse (kvg consumed by k/v post)

  ln_kernel<true><<<8192, 256, 0, stream>>>(x, g_norm, xn);
  cast_bf16<<<8192, 256, 0, stream>>>(context, ctxb, 2097152);
  transpose_cast<<<dim3(32, 32), 256, 0, stream>>>(Wq, wqT, 1024, 1024);
  transpose_cast<<<dim3(64, 32), 256, 0, stream>>>(Wkv, wkvT, 1024, 2048);
  transpose_cast<<<dim3(32, 32), 256, 0, stream>>>(Wout, woutT, 1024, 1024);
  gemm_bt<<<dim3(8, 64), 256, 0, stream>>>(xn, wqT, qg, 8192, 1024, 1024);
  gemm_bt<<<dim3(16, 64), 256, 0, stream>>>(ctxb, wkvT, kvg, 8192, 2048, 1024);
  q_post<<<131072, 64, 0, stream>>>(qg, q_scale, qnb);
  k_post<<<131072, 64, 0, stream>>>(kvg, k_scale, knb);
  v_post<<<dim3(32, 64), 256, 0, stream>>>(kvg, vtb);
  null_tail<<<64, 64, 0, stream>>>(null_kv, k_scale, knb, vtb);
  attn_kernel<<<dim3(32, 64), 256, 0, stream>>>(qnb, knb, vtb, attn_out);
  gemm_bt<<<dim3(8, 64), 256, 0, stream>>>(attn_out, woutT, outg, 8192, 1024, 1024);
  ln_kernel<false><<<8192, 256, 0, stream>>>(outg, g_out, out);
}

// Round 2
// 492.597 us; speedup vs baseline: 1.5580x; 1.5580x over previous
//
#include <hip/hip_runtime.h>

// Problem constants
#define BATCH 4
#define NSEQ 2048
#define MSEQ 2048
#define DIM 1024
#define HEADS 16
#define DHEAD 64
#define INNER 1024
#define KVLEN 2049          // null token + MSEQ
#define KVPAD 2176          // 17 * 128

typedef unsigned short u16;
typedef unsigned int u32;
typedef __bf16 bf16x8 __attribute__((ext_vector_type(8)));
typedef float f32x4 __attribute__((ext_vector_type(4)));

__device__ inline u16 f2bf(float f) {
  u32 u = __builtin_bit_cast(u32, f);
  u = (u + 0x7fffu + ((u >> 16) & 1u)) >> 16;
  return (u16)u;
}
__device__ inline float bf2f(u16 x) {
  return __builtin_bit_cast(float, (u32)x << 16);
}

__device__ __forceinline__ void gld_lds16(const void* g, void* l) {
  __builtin_amdgcn_global_load_lds(
      (const __attribute__((address_space(1))) void*)g,
      (__attribute__((address_space(3))) void*)l, 16, 0, 0);
}

// ---------------- LayerNorm (row of 1024), output bf16 or fp32 ----------------
template <bool OUT_BF16>
__global__ __launch_bounds__(256) void ln_kernel(const float* __restrict__ x,
                                                 const float* __restrict__ g,
                                                 void* __restrict__ out) {
  const int row = blockIdx.x;
  const int t = threadIdx.x;
  const float4 v = ((const float4*)(x + (size_t)row * 1024))[t];
  float sum = v.x + v.y + v.z + v.w;
  float sq = v.x * v.x + v.y * v.y + v.z * v.z + v.w * v.w;
  for (int m = 1; m < 64; m <<= 1) {
    sum += __shfl_xor(sum, m, 64);
    sq += __shfl_xor(sq, m, 64);
  }
  __shared__ float red[8];
  const int w = t >> 6, l = t & 63;
  if (l == 0) { red[w] = sum; red[4 + w] = sq; }
  __syncthreads();
  sum = red[0] + red[1] + red[2] + red[3];
  sq = red[4] + red[5] + red[6] + red[7];
  const float mean = sum * (1.0f / 1024.0f);
  const float var = sq * (1.0f / 1024.0f) - mean * mean;
  const float rstd = rsqrtf(var + 1e-5f);
  const float4 gv = ((const float4*)g)[t];
  float o0 = (v.x - mean) * rstd * gv.x;
  float o1 = (v.y - mean) * rstd * gv.y;
  float o2 = (v.z - mean) * rstd * gv.z;
  float o3 = (v.w - mean) * rstd * gv.w;
  if (OUT_BF16) {
    ushort4 ov;
    ov.x = f2bf(o0); ov.y = f2bf(o1); ov.z = f2bf(o2); ov.w = f2bf(o3);
    ((ushort4*)((u16*)out + (size_t)row * 1024))[t] = ov;
  } else {
    float4 ov;
    ov.x = o0; ov.y = o1; ov.z = o2; ov.w = o3;
    ((float4*)((float*)out + (size_t)row * 1024))[t] = ov;
  }
}

// ---------------- fp32 -> bf16 cast (vectorized by 4) ----------------
__global__ __launch_bounds__(256) void cast_bf16(const float* __restrict__ in,
                                                 u16* __restrict__ out, int n4) {
  int i = blockIdx.x * 256 + threadIdx.x;
  if (i < n4) {
    float4 v = ((const float4*)in)[i];
    ushort4 o;
    o.x = f2bf(v.x); o.y = f2bf(v.y); o.z = f2bf(v.z); o.w = f2bf(v.w);
    ((ushort4*)out)[i] = o;
  }
}

// ---------------- W[K][N] fp32 -> WT[N][K] bf16 (tiled transpose) ----------------
__global__ __launch_bounds__(256) void transpose_cast(const float* __restrict__ W,
                                                      u16* __restrict__ WT, int K, int N) {
  __shared__ float tile[32][33];
  const int tx = threadIdx.x & 31, ty = threadIdx.x >> 5;  // ty 0..7
  const int k0 = blockIdx.y * 32, n0 = blockIdx.x * 32;
  for (int r = ty; r < 32; r += 8) tile[r][tx] = W[(size_t)(k0 + r) * N + n0 + tx];
  __syncthreads();
  for (int r = ty; r < 32; r += 8) WT[(size_t)(n0 + r) * K + k0 + tx] = f2bf(tile[tx][r]);
}

// ---------------- bf16 GEMM: C[M][N] = A[M][K] @ Bt[N][K]^T ----------------
// 128x128 tile, BK=32, 4 waves in 2x2, each wave 4x4 of 16x16x32 MFMA.
// global_load_lds width-16 staging (m97 pattern).
template <bool OUT_BF16>
__global__ __launch_bounds__(256) void gemm_bt(const u16* __restrict__ A,
                                               const u16* __restrict__ Bt,
                                               void* __restrict__ Cv,
                                               int M, int N, int K) {
  __shared__ __align__(16) u16 As[128 * 32];
  __shared__ __align__(16) u16 Bs[128 * 32];
  const int t = threadIdx.x;
  const int w = t >> 6, l = t & 63, l15 = l & 15, lq = l >> 4;
  const int m0 = blockIdx.y * 128, n0 = blockIdx.x * 128;
  const int wm = (w >> 1) * 64, wn = (w & 1) * 64;
  const int lr = l >> 2;           // 0..15 row-within-chunk
  const int lo = (l & 3) * 8;      // u16 offset within row: 0,8,16,24
  f32x4 acc[4][4] = {};
  for (int k0 = 0; k0 < K; k0 += 32) {
#pragma unroll
    for (int it = 0; it < 2; it++) {
      const int row = (w * 2 + it) * 16 + lr;   // 0..127
      gld_lds16(&A[(size_t)(m0 + row) * K + k0 + lo], &As[row * 32 + lo]);
      gld_lds16(&Bt[(size_t)(n0 + row) * K + k0 + lo], &Bs[row * 32 + lo]);
    }
    __syncthreads();
    bf16x8 af[4], bfr[4];
#pragma unroll
    for (int i = 0; i < 4; i++) af[i] = *(bf16x8*)&As[(wm + i * 16 + l15) * 32 + lq * 8];
#pragma unroll
    for (int j = 0; j < 4; j++) bfr[j] = *(bf16x8*)&Bs[(wn + j * 16 + l15) * 32 + lq * 8];
#pragma unroll
    for (int i = 0; i < 4; i++)
#pragma unroll
      for (int j = 0; j < 4; j++)
        acc[i][j] = __builtin_amdgcn_mfma_f32_16x16x32_bf16(af[i], bfr[j], acc[i][j], 0, 0, 0);
    __syncthreads();
  }
#pragma unroll
  for (int i = 0; i < 4; i++)
#pragma unroll
    for (int j = 0; j < 4; j++)
#pragma unroll
      for (int r = 0; r < 4; r++) {
        const size_t off = (size_t)(m0 + wm + i * 16 + lq * 4 + r) * N + n0 + wn + j * 16 + l15;
        if (OUT_BF16) ((u16*)Cv)[off] = f2bf(acc[i][j][r]);
        else ((float*)Cv)[off] = acc[i][j][r];
      }
}

// ---------------- q post: l2norm * q_scale * SCALE -> qn[b,h,n,64] bf16 ----------------
__global__ __launch_bounds__(256) void q_post(const u16* __restrict__ qg,
                                              const float* __restrict__ q_scale,
                                              u16* __restrict__ qn) {
  const int idx = blockIdx.x * 4 + (threadIdx.x >> 6);
  const int d = threadIdx.x & 63;
  const int h = idx & 15, row = idx >> 4;  // row = b*2048 + n
  float v = bf2f(qg[(size_t)row * 1024 + h * 64 + d]);
  float ss = v * v;
  for (int m = 1; m < 64; m <<= 1) ss += __shfl_xor(ss, m, 64);
  float inv = 1.0f / fmaxf(sqrtf(ss), 1e-12f);
  float o = v * inv * q_scale[d] * 8.0f;
  const int b = row >> 11, n = row & 2047;
  qn[(((size_t)b * 16 + h) * 2048 + n) * 64 + d] = f2bf(o);
}

// ---------------- k post: l2norm * k_scale -> kn[b,h,m+1,64] bf16 ----------------
__global__ __launch_bounds__(256) void k_post(const u16* __restrict__ kvg,
                                              const float* __restrict__ k_scale,
                                              u16* __restrict__ kn) {
  const int idx = blockIdx.x * 4 + (threadIdx.x >> 6);
  const int d = threadIdx.x & 63;
  const int h = idx & 15, row = idx >> 4;  // row = b*2048 + m
  float v = bf2f(kvg[(size_t)row * 2048 + h * 64 + d]);
  float ss = v * v;
  for (int m = 1; m < 64; m <<= 1) ss += __shfl_xor(ss, m, 64);
  float inv = 1.0f / fmaxf(sqrtf(ss), 1e-12f);
  float o = v * inv * k_scale[d];
  const int b = row >> 11, mm = row & 2047;
  kn[(((size_t)b * 16 + h) * (size_t)KVPAD + (mm + 1)) * 64 + d] = f2bf(o);
}

// ---------------- v post: transpose to vt[b,h,64,KVPAD] bf16 (offset +1 for null) ----------------
__global__ __launch_bounds__(256) void v_post(const u16* __restrict__ kvg,
                                              u16* __restrict__ vt) {
  __shared__ u16 tile[64][68];
  const int bh = blockIdx.y, mt = blockIdx.x;
  const int tx = threadIdx.x & 63, ty = threadIdx.x >> 6;
  const int b = bh >> 4, h = bh & 15;
  const int m0 = mt * 64;
  for (int r = ty; r < 64; r += 4)
    tile[tx][r] = kvg[(size_t)(b * 2048 + m0 + r) * 2048 + 1024 + h * 64 + tx];
  __syncthreads();
  for (int d = ty; d < 64; d += 4)
    vt[((size_t)bh * 64 + d) * KVPAD + 1 + m0 + tx] = tile[d][tx];
}

// ---------------- null token + tail zeroing ----------------
__global__ __launch_bounds__(64) void null_tail(const float* __restrict__ null_kv,
                                                const float* __restrict__ k_scale,
                                                u16* __restrict__ kn, u16* __restrict__ vt) {
  const int bh = blockIdx.x, d = threadIdx.x;
  float nk = null_kv[d];
  float nv = null_kv[64 + d];
  float ss = nk * nk;
  for (int m = 1; m < 64; m <<= 1) ss += __shfl_xor(ss, m, 64);
  float inv = 1.0f / fmaxf(sqrtf(ss), 1e-12f);
  kn[((size_t)bh * KVPAD) * 64 + d] = f2bf(nk * inv * k_scale[d]);
  vt[((size_t)bh * 64 + d) * KVPAD] = f2bf(nv);
  for (int m = KVLEN; m < KVPAD; m++) kn[((size_t)bh * KVPAD + m) * 64 + d] = 0;
  u16* vrow = vt + ((size_t)bh * 64 + d) * KVPAD;
  for (int m = KVLEN; m < KVPAD; m++) vrow[m] = 0;
}

// ---------------- flash attention, fixed-max softmax ----------------
// |sim| <= 8 by Cauchy-Schwarz (l2norm'd q,k; scales==1; SCALE=8) -> static max 8.
// Q tile 64 rows, KV tiles of 128, 17 iters. Ps aliases Ks (wave-private rows).
// LDS: Ks 128x72 (18432 B) + Vs 64x136 (17408 B) = 35840 B -> 4 blocks/CU.
__global__ __launch_bounds__(256, 4) void attn_kernel(const u16* __restrict__ qn,
                                                      const u16* __restrict__ kn,
                                                      const u16* __restrict__ vt,
                                                      u16* __restrict__ aout) {
  __shared__ __align__(16) u16 KPs[128 * 72];  // K tile (stride 72) / P tile (stride 136)
  __shared__ __align__(16) u16 Vs[64 * 136];   // V^T tile, stride 136
  const int qt = blockIdx.x, bh = blockIdx.y;
  const int b = bh >> 4, h = bh & 15;
  const int t = threadIdx.x, w = t >> 6, l = t & 63, l15 = l & 15, lq = l >> 4;

  // Q fragments straight from global (loop-invariant)
  bf16x8 aqf[2];
  {
    const u16* qrow = qn + ((size_t)bh * 2048 + qt * 64 + w * 16 + l15) * 64 + lq * 8;
    aqf[0] = *(const bf16x8*)(qrow);
    aqf[1] = *(const bf16x8*)(qrow + 32);
  }

  // staging address precompute
  const int krow = t >> 3, kko = (t & 7) * 8;
  const u16* kgp = kn + (size_t)bh * KVPAD * 64 + krow * 64 + kko;
  u16* klp = (u16*)&KPs[krow * 72 + kko];
  const int vd = t >> 4, voff = (t & 15) * 8;
  const u16* vgp = vt + ((size_t)bh * 64 + vd) * KVPAD + voff;
  u16* vlp = (u16*)&Vs[vd * 136 + voff];

  f32x4 O[4] = {};
  float lsum[4] = {0.f, 0.f, 0.f, 0.f};
  const float LOG2E = 1.44269504f;
  const float MBIAS = -8.0f * 1.44269504f;  // exp(s-8) = 2^(s*log2e + MBIAS)

  for (int kt = 0; kt < 17; kt++) {
    // ---- stage K (128x64) and V^T (64x128) into padded LDS ----
#pragma unroll
    for (int i = 0; i < 4; i++)
      *(uint4*)(klp + i * 2304) = *(const uint4*)(kgp + kt * 8192 + i * 2048);
#pragma unroll
    for (int i = 0; i < 4; i++)
      *(uint4*)(vlp + i * 2176) = *(const uint4*)(vgp + kt * 128 + (size_t)i * 16 * KVPAD);
    __syncthreads();

    // ---- S = Q K^T (wave w owns q rows w*16..w*16+15) ----
    f32x4 S[8] = {};
#pragma unroll
    for (int ks = 0; ks < 2; ks++)
#pragma unroll
      for (int j = 0; j < 8; j++) {
        bf16x8 bk = *(bf16x8*)&KPs[(j * 16 + l15) * 72 + ks * 32 + lq * 8];
        S[j] = __builtin_amdgcn_mfma_f32_16x16x32_bf16(aqf[ks], bk, S[j], 0, 0, 0);
      }
    __syncthreads();  // all waves done reading K before P overwrites it

    // ---- P = exp(S - 8), accumulate row sums (no cross-lane work) ----
    const bool last = (kt == 16);
#pragma unroll
    for (int j = 0; j < 8; j++)
#pragma unroll
      for (int r = 0; r < 4; r++) {
        float p = __builtin_amdgcn_exp2f(fmaf(S[j][r], LOG2E, MBIAS));
        if (last && ((j << 4) | l15) != 0) p = 0.f;  // only global col 2048 valid
        lsum[r] += p;
        u32 bb = __builtin_bit_cast(u32, p);
        KPs[(w * 16 + lq * 4 + r) * 136 + j * 16 + l15] = (u16)((bb + 0x8000u) >> 16);
      }
    // no barrier: wave reads back only its own P rows

    // ---- O += P V ----
#pragma unroll
    for (int ks = 0; ks < 4; ks++) {
      bf16x8 ap = *(bf16x8*)&KPs[(w * 16 + l15) * 136 + ks * 32 + lq * 8];
#pragma unroll
      for (int nt = 0; nt < 4; nt++) {
        bf16x8 bv = *(bf16x8*)&Vs[(nt * 16 + l15) * 136 + ks * 32 + lq * 8];
        O[nt] = __builtin_amdgcn_mfma_f32_16x16x32_bf16(ap, bv, O[nt], 0, 0, 0);
      }
    }
    __syncthreads();  // Ks/Ps/Vs reads done before next staging
  }

  // ---- final row-sum reduction (once per block) + normalize + store ----
#pragma unroll
  for (int r = 0; r < 4; r++)
#pragma unroll
    for (int m = 1; m < 16; m <<= 1) lsum[r] += __shfl_xor(lsum[r], m, 64);
#pragma unroll
  for (int nt = 0; nt < 4; nt++)
#pragma unroll
    for (int r = 0; r < 4; r++) {
      int row = qt * 64 + w * 16 + lq * 4 + r;
      int col = h * 64 + nt * 16 + l15;
      float val = O[nt][r] / lsum[r];
      aout[((size_t)b * 2048 + row) * 1024 + col] = f2bf(val);
    }
}

// ---------------- host launch ----------------
extern "C" void kernel_launch(void* const* d_in, const int* in_sizes, int n_in,
                              void* d_out, int out_size, void* d_ws, size_t ws_size,
                              hipStream_t stream) {
  const float* x = (const float*)d_in[0];
  const float* context = (const float*)d_in[1];
  const float* g_norm = (const float*)d_in[2];
  const float* null_kv = (const float*)d_in[3];
  const float* Wq = (const float*)d_in[4];
  const float* Wkv = (const float*)d_in[5];
  const float* q_scale = (const float*)d_in[6];
  const float* k_scale = (const float*)d_in[7];
  const float* Wout = (const float*)d_in[8];
  const float* g_out = (const float*)d_in[9];
  float* out = (float*)d_out;

  char* ws = (char*)d_ws;
  u16* xn = (u16*)(ws);                      // 16,777,216 B
  u16* ctxb = (u16*)(ws + 16777216);         // 16,777,216
  u16* wqT = (u16*)(ws + 33554432);          // 2,097,152
  u16* wkvT = (u16*)(ws + 35651584);         // 4,194,304
  u16* woutT = (u16*)(ws + 39845888);        // 2,097,152
  u16* qg = (u16*)(ws + 41943040);           // 16,777,216 (bf16 q gemm out)
  u16* kvg = (u16*)(ws + 58720256);          // 33,554,432 (bf16 kv gemm out)
  u16* qnb = (u16*)(ws + 92274688);          // 16,777,216
  u16* knb = (u16*)(ws + 109051904);         // 17,825,792
  u16* vtb = (u16*)(ws + 126877696);         // 17,825,792
  float* outg = (float*)(ws + 144703488);    // 33,554,432 -> total 178,257,920
  u16* attn_out = qg;                        // reuse (qg consumed by q_post)

  ln_kernel<true><<<8192, 256, 0, stream>>>(x, g_norm, xn);
  cast_bf16<<<8192, 256, 0, stream>>>(context, ctxb, 2097152);
  transpose_cast<<<dim3(32, 32), 256, 0, stream>>>(Wq, wqT, 1024, 1024);
  transpose_cast<<<dim3(64, 32), 256, 0, stream>>>(Wkv, wkvT, 1024, 2048);
  transpose_cast<<<dim3(32, 32), 256, 0, stream>>>(Wout, woutT, 1024, 1024);
  gemm_bt<true><<<dim3(8, 64), 256, 0, stream>>>(xn, wqT, qg, 8192, 1024, 1024);
  gemm_bt<true><<<dim3(16, 64), 256, 0, stream>>>(ctxb, wkvT, kvg, 8192, 2048, 1024);
  q_post<<<32768, 256, 0, stream>>>(qg, q_scale, qnb);
  k_post<<<32768, 256, 0, stream>>>(kvg, k_scale, knb);
  v_post<<<dim3(32, 64), 256, 0, stream>>>(kvg, vtb);
  null_tail<<<64, 64, 0, stream>>>(null_kv, k_scale, knb, vtb);
  attn_kernel<<<dim3(32, 64), 256, 0, stream>>>(qnb, knb, vtb, attn_out);
  gemm_bt<false><<<dim3(8, 64), 256, 0, stream>>>(attn_out, woutT, outg, 8192, 1024, 1024);
  ln_kernel<false><<<8192, 256, 0, stream>>>(outg, g_out, out);
}

// Round 5
// 464.959 us; speedup vs baseline: 1.6507x; 1.0594x over previous
//
#include <hip/hip_runtime.h>

// Problem constants
#define BATCH 4
#define NSEQ 2048
#define MSEQ 2048
#define DIM 1024
#define HEADS 16
#define DHEAD 64
#define INNER 1024
#define KVLEN 2049          // null token + MSEQ
#define KVPAD 2176          // 17 * 128

typedef unsigned short u16;
typedef unsigned int u32;
typedef __bf16 bf16x8 __attribute__((ext_vector_type(8)));
typedef float f32x4 __attribute__((ext_vector_type(4)));

__device__ inline u16 f2bf(float f) {
  u32 u = __builtin_bit_cast(u32, f);
  u = (u + 0x7fffu + ((u >> 16) & 1u)) >> 16;
  return (u16)u;
}
__device__ inline float bf2f(u16 x) {
  return __builtin_bit_cast(float, (u32)x << 16);
}

__device__ __forceinline__ void gld_lds16(const void* g, void* l) {
  __builtin_amdgcn_global_load_lds(
      (const __attribute__((address_space(1))) void*)g,
      (__attribute__((address_space(3))) void*)l, 16, 0, 0);
}

// ---------------- LayerNorm (row of 1024), output bf16 or fp32 ----------------
template <bool OUT_BF16>
__global__ __launch_bounds__(256) void ln_kernel(const float* __restrict__ x,
                                                 const float* __restrict__ g,
                                                 void* __restrict__ out) {
  const int row = blockIdx.x;
  const int t = threadIdx.x;
  const float4 v = ((const float4*)(x + (size_t)row * 1024))[t];
  float sum = v.x + v.y + v.z + v.w;
  float sq = v.x * v.x + v.y * v.y + v.z * v.z + v.w * v.w;
  for (int m = 1; m < 64; m <<= 1) {
    sum += __shfl_xor(sum, m, 64);
    sq += __shfl_xor(sq, m, 64);
  }
  __shared__ float red[8];
  const int w = t >> 6, l = t & 63;
  if (l == 0) { red[w] = sum; red[4 + w] = sq; }
  __syncthreads();
  sum = red[0] + red[1] + red[2] + red[3];
  sq = red[4] + red[5] + red[6] + red[7];
  const float mean = sum * (1.0f / 1024.0f);
  const float var = sq * (1.0f / 1024.0f) - mean * mean;
  const float rstd = rsqrtf(var + 1e-5f);
  const float4 gv = ((const float4*)g)[t];
  float o0 = (v.x - mean) * rstd * gv.x;
  float o1 = (v.y - mean) * rstd * gv.y;
  float o2 = (v.z - mean) * rstd * gv.z;
  float o3 = (v.w - mean) * rstd * gv.w;
  if (OUT_BF16) {
    ushort4 ov;
    ov.x = f2bf(o0); ov.y = f2bf(o1); ov.z = f2bf(o2); ov.w = f2bf(o3);
    ((ushort4*)((u16*)out + (size_t)row * 1024))[t] = ov;
  } else {
    float4 ov;
    ov.x = o0; ov.y = o1; ov.z = o2; ov.w = o3;
    ((float4*)((float*)out + (size_t)row * 1024))[t] = ov;
  }
}

// ---------------- fp32 -> bf16 cast (vectorized by 4) ----------------
__global__ __launch_bounds__(256) void cast_bf16(const float* __restrict__ in,
                                                 u16* __restrict__ out, int n4) {
  int i = blockIdx.x * 256 + threadIdx.x;
  if (i < n4) {
    float4 v = ((const float4*)in)[i];
    ushort4 o;
    o.x = f2bf(v.x); o.y = f2bf(v.y); o.z = f2bf(v.z); o.w = f2bf(v.w);
    ((ushort4*)out)[i] = o;
  }
}

// ---------------- W[K][N] fp32 -> WT[N][K] bf16 (tiled transpose) ----------------
__global__ __launch_bounds__(256) void transpose_cast(const float* __restrict__ W,
                                                      u16* __restrict__ WT, int K, int N) {
  __shared__ float tile[32][33];
  const int tx = threadIdx.x & 31, ty = threadIdx.x >> 5;  // ty 0..7
  const int k0 = blockIdx.y * 32, n0 = blockIdx.x * 32;
  for (int r = ty; r < 32; r += 8) tile[r][tx] = W[(size_t)(k0 + r) * N + n0 + tx];
  __syncthreads();
  for (int r = ty; r < 32; r += 8) WT[(size_t)(n0 + r) * K + k0 + tx] = f2bf(tile[tx][r]);
}

// ---------------- bf16 GEMM: C = A[M][K] @ Bt[N][K]^T ----------------
// MODE 0: fp32 C row-major. MODE 1: bf16 C row-major.
// MODE 2: fused q_post -> l2norm(head)*scale*8, write qn[b,h,n,64].
// MODE 3: fused kv post -> heads 0..15: l2norm*k_scale -> kn[b,h,m+1,64];
//                          heads 16..31: plain bf16 -> aux[row][ (h-16)*64+d ].
template <int MODE>
__global__ __launch_bounds__(256) void gemm_bt(const u16* __restrict__ A,
                                               const u16* __restrict__ Bt,
                                               void* __restrict__ Cv,
                                               int M, int N, int K,
                                               const float* __restrict__ scale,
                                               u16* __restrict__ aux) {
  __shared__ __align__(16) u16 As[128 * 32];
  __shared__ __align__(16) u16 Bs[128 * 32];
  const int t = threadIdx.x;
  const int w = t >> 6, l = t & 63, l15 = l & 15, lq = l >> 4;
  const int m0 = blockIdx.y * 128, n0 = blockIdx.x * 128;
  const int wm = (w >> 1) * 64, wn = (w & 1) * 64;
  const int lr = l >> 2;           // 0..15 row-within-chunk
  const int lo = (l & 3) * 8;      // u16 offset within row: 0,8,16,24
  f32x4 acc[4][4] = {};
  for (int k0 = 0; k0 < K; k0 += 32) {
#pragma unroll
    for (int it = 0; it < 2; it++) {
      const int row = (w * 2 + it) * 16 + lr;   // 0..127
      gld_lds16(&A[(size_t)(m0 + row) * K + k0 + lo], &As[row * 32 + lo]);
      gld_lds16(&Bt[(size_t)(n0 + row) * K + k0 + lo], &Bs[row * 32 + lo]);
    }
    __syncthreads();
    bf16x8 af[4], bfr[4];
#pragma unroll
    for (int i = 0; i < 4; i++) af[i] = *(bf16x8*)&As[(wm + i * 16 + l15) * 32 + lq * 8];
#pragma unroll
    for (int j = 0; j < 4; j++) bfr[j] = *(bf16x8*)&Bs[(wn + j * 16 + l15) * 32 + lq * 8];
#pragma unroll
    for (int i = 0; i < 4; i++)
#pragma unroll
      for (int j = 0; j < 4; j++)
        acc[i][j] = __builtin_amdgcn_mfma_f32_16x16x32_bf16(af[i], bfr[j], acc[i][j], 0, 0, 0);
    __syncthreads();
  }

  if (MODE <= 1) {
#pragma unroll
    for (int i = 0; i < 4; i++)
#pragma unroll
      for (int j = 0; j < 4; j++)
#pragma unroll
        for (int r = 0; r < 4; r++) {
          const size_t off =
              (size_t)(m0 + wm + i * 16 + lq * 4 + r) * N + n0 + wn + j * 16 + l15;
          if (MODE == 1) ((u16*)Cv)[off] = f2bf(acc[i][j][r]);
          else ((float*)Cv)[off] = acc[i][j][r];
        }
    return;
  }

  const int head = (n0 + wn) >> 6;  // wave-uniform
  if (MODE == 3 && head >= 16) {
    // V columns: plain bf16 into compact aux[row][ (head-16)*64 + d ]
#pragma unroll
    for (int i = 0; i < 4; i++)
#pragma unroll
      for (int j = 0; j < 4; j++)
#pragma unroll
        for (int r = 0; r < 4; r++) {
          const int row = m0 + wm + i * 16 + lq * 4 + r;
          aux[(size_t)row * 1024 + (head - 16) * 64 + j * 16 + l15] = f2bf(acc[i][j][r]);
        }
    return;
  }
  // l2norm over the 64-col head + scale (q: *8)
  float sc[4];
#pragma unroll
  for (int j = 0; j < 4; j++) sc[j] = scale[j * 16 + l15];
  const float mul = (MODE == 2) ? 8.0f : 1.0f;
  u16* outp = (u16*)Cv;
#pragma unroll
  for (int i = 0; i < 4; i++)
#pragma unroll
    for (int r = 0; r < 4; r++) {
      float ss = 0.f;
#pragma unroll
      for (int j = 0; j < 4; j++) ss = fmaf(acc[i][j][r], acc[i][j][r], ss);
#pragma unroll
      for (int m = 1; m < 16; m <<= 1) ss += __shfl_xor(ss, m, 64);
      const float inv = mul / fmaxf(sqrtf(ss), 1e-12f);
      const int row = m0 + wm + i * 16 + lq * 4 + r;
      const int b = row >> 11, n = row & 2047;
      const size_t base = (MODE == 2)
          ? (((size_t)b * 16 + head) * 2048 + n) * 64
          : (((size_t)b * 16 + head) * (size_t)KVPAD + n + 1) * 64;
#pragma unroll
      for (int j = 0; j < 4; j++)
        outp[base + j * 16 + l15] = f2bf(acc[i][j][r] * inv * sc[j]);
    }
}

// ---------------- v post: transpose vg[row][h*64+d] -> vt[b,h,64,KVPAD] ----------------
__global__ __launch_bounds__(256) void v_post(const u16* __restrict__ vg,
                                              u16* __restrict__ vt) {
  __shared__ u16 tile[64][68];
  const int bh = blockIdx.y, mt = blockIdx.x;
  const int tx = threadIdx.x & 63, ty = threadIdx.x >> 6;
  const int b = bh >> 4, h = bh & 15;
  const int m0 = mt * 64;
  for (int r = ty; r < 64; r += 4)
    tile[tx][r] = vg[(size_t)(b * 2048 + m0 + r) * 1024 + h * 64 + tx];
  __syncthreads();
  for (int d = ty; d < 64; d += 4)
    vt[((size_t)bh * 64 + d) * KVPAD + 1 + m0 + tx] = tile[d][tx];
}

// ---------------- null token + tail zeroing ----------------
__global__ __launch_bounds__(64) void null_tail(const float* __restrict__ null_kv,
                                                const float* __restrict__ k_scale,
                                                u16* __restrict__ kn, u16* __restrict__ vt) {
  const int bh = blockIdx.x, d = threadIdx.x;
  float nk = null_kv[d];
  float nv = null_kv[64 + d];
  float ss = nk * nk;
  for (int m = 1; m < 64; m <<= 1) ss += __shfl_xor(ss, m, 64);
  float inv = 1.0f / fmaxf(sqrtf(ss), 1e-12f);
  kn[((size_t)bh * KVPAD) * 64 + d] = f2bf(nk * inv * k_scale[d]);
  vt[((size_t)bh * 64 + d) * KVPAD] = f2bf(nv);
  for (int m = KVLEN; m < KVPAD; m++) kn[((size_t)bh * KVPAD + m) * 64 + d] = 0;
  u16* vrow = vt + ((size_t)bh * 64 + d) * KVPAD;
  for (int m = KVLEN; m < KVPAD; m++) vrow[m] = 0;
}

// ---------------- flash attention, fixed-max softmax (R2-verbatim, known-pass) ----------------
// |sim| <= 8 by Cauchy-Schwarz (l2norm'd q,k; scales==1; SCALE=8) -> static max 8.
// Q tile 64 rows, KV tiles of 128, 17 iters. Ps aliases Ks (wave-private rows).
// LDS: Ks 128x72 (18432 B) + Vs 64x136 (17408 B) = 35840 B -> 4 blocks/CU.
__global__ __launch_bounds__(256, 4) void attn_kernel(const u16* __restrict__ qn,
                                                      const u16* __restrict__ kn,
                                                      const u16* __restrict__ vt,
                                                      u16* __restrict__ aout) {
  __shared__ __align__(16) u16 KPs[128 * 72];  // K tile (stride 72) / P tile (stride 136)
  __shared__ __align__(16) u16 Vs[64 * 136];   // V^T tile, stride 136
  const int qt = blockIdx.x, bh = blockIdx.y;
  const int b = bh >> 4, h = bh & 15;
  const int t = threadIdx.x, w = t >> 6, l = t & 63, l15 = l & 15, lq = l >> 4;

  // Q fragments straight from global (loop-invariant)
  bf16x8 aqf[2];
  {
    const u16* qrow = qn + ((size_t)bh * 2048 + qt * 64 + w * 16 + l15) * 64 + lq * 8;
    aqf[0] = *(const bf16x8*)(qrow);
    aqf[1] = *(const bf16x8*)(qrow + 32);
  }

  // staging address precompute
  const int krow = t >> 3, kko = (t & 7) * 8;
  const u16* kgp = kn + (size_t)bh * KVPAD * 64 + krow * 64 + kko;
  u16* klp = (u16*)&KPs[krow * 72 + kko];
  const int vd = t >> 4, voff = (t & 15) * 8;
  const u16* vgp = vt + ((size_t)bh * 64 + vd) * KVPAD + voff;
  u16* vlp = (u16*)&Vs[vd * 136 + voff];

  f32x4 O[4] = {};
  float lsum[4] = {0.f, 0.f, 0.f, 0.f};
  const float LOG2E = 1.44269504f;
  const float MBIAS = -8.0f * 1.44269504f;  // exp(s-8) = 2^(s*log2e + MBIAS)

  for (int kt = 0; kt < 17; kt++) {
    // ---- stage K (128x64) and V^T (64x128) into padded LDS ----
#pragma unroll
    for (int i = 0; i < 4; i++)
      *(uint4*)(klp + i * 2304) = *(const uint4*)(kgp + kt * 8192 + i * 2048);
#pragma unroll
    for (int i = 0; i < 4; i++)
      *(uint4*)(vlp + i * 2176) = *(const uint4*)(vgp + kt * 128 + (size_t)i * 16 * KVPAD);
    __syncthreads();

    // ---- S = Q K^T (wave w owns q rows w*16..w*16+15) ----
    f32x4 S[8] = {};
#pragma unroll
    for (int ks = 0; ks < 2; ks++)
#pragma unroll
      for (int j = 0; j < 8; j++) {
        bf16x8 bk = *(bf16x8*)&KPs[(j * 16 + l15) * 72 + ks * 32 + lq * 8];
        S[j] = __builtin_amdgcn_mfma_f32_16x16x32_bf16(aqf[ks], bk, S[j], 0, 0, 0);
      }
    __syncthreads();  // all waves done reading K before P overwrites it

    // ---- P = exp(S - 8), accumulate row sums (no cross-lane work) ----
    const bool last = (kt == 16);
#pragma unroll
    for (int j = 0; j < 8; j++)
#pragma unroll
      for (int r = 0; r < 4; r++) {
        float p = __builtin_amdgcn_exp2f(fmaf(S[j][r], LOG2E, MBIAS));
        if (last && ((j << 4) | l15) != 0) p = 0.f;  // only global col 2048 valid
        lsum[r] += p;
        u32 bb = __builtin_bit_cast(u32, p);
        KPs[(w * 16 + lq * 4 + r) * 136 + j * 16 + l15] = (u16)((bb + 0x8000u) >> 16);
      }
    // no barrier: wave reads back only its own P rows

    // ---- O += P V ----
#pragma unroll
    for (int ks = 0; ks < 4; ks++) {
      bf16x8 ap = *(bf16x8*)&KPs[(w * 16 + l15) * 136 + ks * 32 + lq * 8];
#pragma unroll
      for (int nt = 0; nt < 4; nt++) {
        bf16x8 bv = *(bf16x8*)&Vs[(nt * 16 + l15) * 136 + ks * 32 + lq * 8];
        O[nt] = __builtin_amdgcn_mfma_f32_16x16x32_bf16(ap, bv, O[nt], 0, 0, 0);
      }
    }
    __syncthreads();  // Ks/Ps/Vs reads done before next staging
  }

  // ---- final row-sum reduction (once per block) + normalize + store ----
#pragma unroll
  for (int r = 0; r < 4; r++)
#pragma unroll
    for (int m = 1; m < 16; m <<= 1) lsum[r] += __shfl_xor(lsum[r], m, 64);
#pragma unroll
  for (int nt = 0; nt < 4; nt++)
#pragma unroll
    for (int r = 0; r < 4; r++) {
      int row = qt * 64 + w * 16 + lq * 4 + r;
      int col = h * 64 + nt * 16 + l15;
      float val = O[nt][r] / lsum[r];
      aout[((size_t)b * 2048 + row) * 1024 + col] = f2bf(val);
    }
}

// ---------------- host launch ----------------
extern "C" void kernel_launch(void* const* d_in, const int* in_sizes, int n_in,
                              void* d_out, int out_size, void* d_ws, size_t ws_size,
                              hipStream_t stream) {
  const float* x = (const float*)d_in[0];
  const float* context = (const float*)d_in[1];
  const float* g_norm = (const float*)d_in[2];
  const float* null_kv = (const float*)d_in[3];
  const float* Wq = (const float*)d_in[4];
  const float* Wkv = (const float*)d_in[5];
  const float* q_scale = (const float*)d_in[6];
  const float* k_scale = (const float*)d_in[7];
  const float* Wout = (const float*)d_in[8];
  const float* g_out = (const float*)d_in[9];
  float* out = (float*)d_out;

  char* ws = (char*)d_ws;
  u16* xn = (u16*)(ws);                      // 16,777,216 B
  u16* ctxb = (u16*)(ws + 16777216);         // 16,777,216
  u16* wqT = (u16*)(ws + 33554432);          // 2,097,152
  u16* wkvT = (u16*)(ws + 35651584);         // 4,194,304
  u16* woutT = (u16*)(ws + 39845888);        // 2,097,152
  u16* qnb = (u16*)(ws + 41943040);          // 16,777,216
  u16* knb = (u16*)(ws + 58720256);          // 17,825,792
  u16* vtb = (u16*)(ws + 76546048);          // 17,825,792
  u16* vg = (u16*)(ws + 94371840);           // 16,777,216
  float* outg = (float*)(ws + 111149056);    // 33,554,432 -> total 144,703,488
  u16* attn_out = vg;                        // vg fully consumed by v_post

  ln_kernel<true><<<8192, 256, 0, stream>>>(x, g_norm, xn);
  cast_bf16<<<8192, 256, 0, stream>>>(context, ctxb, 2097152);
  transpose_cast<<<dim3(32, 32), 256, 0, stream>>>(Wq, wqT, 1024, 1024);
  transpose_cast<<<dim3(64, 32), 256, 0, stream>>>(Wkv, wkvT, 1024, 2048);
  transpose_cast<<<dim3(32, 32), 256, 0, stream>>>(Wout, woutT, 1024, 1024);
  gemm_bt<2><<<dim3(8, 64), 256, 0, stream>>>(xn, wqT, qnb, 8192, 1024, 1024, q_scale, nullptr);
  gemm_bt<3><<<dim3(16, 64), 256, 0, stream>>>(ctxb, wkvT, knb, 8192, 2048, 1024, k_scale, vg);
  v_post<<<dim3(32, 64), 256, 0, stream>>>(vg, vtb);
  null_tail<<<64, 64, 0, stream>>>(null_kv, k_scale, knb, vtb);
  attn_kernel<<<dim3(32, 64), 256, 0, stream>>>(qnb, knb, vtb, attn_out);
  gemm_bt<0><<<dim3(8, 64), 256, 0, stream>>>(attn_out, woutT, outg, 8192, 1024, 1024, nullptr, nullptr);
  ln_kernel<false><<<8192, 256, 0, stream>>>(outg, g_out, out);
}